// Round 5
// baseline (50.214 us; speedup 1.0000x reference)
//
#include <hip/hip_runtime.h>

#define HADN 4096
#define NFEAT 2048
#define INV2PI 0.15915494309189535f

typedef float floatx4 __attribute__((ext_vector_type(4)));

// out-bit <- in-axis mapping of one reference "fwht" (derived by axis tracking):
// bit0<-a6, bit1<-H(a3), bit2<-a7, bit3<-a0, bit4<-a8, bit5<-H(a4),
// bit6<-a9, bit7<-a2, bit8<-a10, bit9<-H(a5), bit10<-a11, bit11<-H(a1)
__device__ __host__ __forceinline__ int pi_map(int q) {
  return  (((q >> 3) & 1))
        | (((q >> 11) & 1) << 1)
        | (((q >> 7) & 1) << 2)
        | (((q >> 1) & 1) << 3)
        | (((q >> 5) & 1) << 4)
        | (((q >> 9) & 1) << 5)
        | (((q >> 0) & 1) << 6)
        | (((q >> 2) & 1) << 7)
        | (((q >> 4) & 1) << 8)
        | (((q >> 6) & 1) << 9)
        | (((q >> 8) & 1) << 10)
        | (((q >> 10) & 1) << 11);
}

__device__ __host__ __forceinline__ int pi_inv_map(int p) {
  return  (((p >> 6) & 1))
        | (((p >> 3) & 1) << 1)
        | (((p >> 7) & 1) << 2)
        | (((p >> 0) & 1) << 3)
        | (((p >> 8) & 1) << 4)
        | (((p >> 4) & 1) << 5)
        | (((p >> 9) & 1) << 6)
        | (((p >> 2) & 1) << 7)
        | (((p >> 10) & 1) << 8)
        | (((p >> 5) & 1) << 9)
        | (((p >> 11) & 1) << 10)
        | (((p >> 1) & 1) << 11);
}

// LDS bank swizzle: XOR bits {6,7,8}^{9,10,11} into bits {2,3,4}.
// Keeps bits 0..1 intact -> float4 stays contiguous & 16B aligned.
__device__ __forceinline__ int swz(int p) {
  return p ^ ((((p >> 6) ^ (p >> 9)) & 7) << 2);
}

template <int BIT>
__device__ __forceinline__ void bfly(float* r) {
#pragma unroll
  for (int e = 0; e < 16; ++e) {
    if ((e & BIT) == 0) {
      const int f = e | BIT;
      const float a = r[e], b = r[f];
      r[e] = a + b;
      r[f] = a - b;
    }
  }
}

// Cross-lane butterfly via DPP quad-perm (VALU, not DS pipe).
// CTRL=0xB1 -> lane^1, CTRL=0x4E -> lane^2. `upper` lane computes partner-own.
template <int CTRL>
__device__ __forceinline__ void dpp_bfly(float* r, bool upper) {
  const unsigned sm = upper ? 0x80000000u : 0u;
#pragma unroll
  for (int e = 0; e < 16; ++e) {
    const int pv = __builtin_amdgcn_update_dpp(
        0, __float_as_int(r[e]), CTRL, 0xF, 0xF, true);
    r[e] = __int_as_float(pv) + __int_as_float(__float_as_int(r[e]) ^ sm);
  }
}

__global__ __launch_bounds__(256) void srf_setup(
    const float* __restrict__ D2, const float* __restrict__ D3,
    const int* __restrict__ perm, const float* __restrict__ bias,
    unsigned* __restrict__ D2sgn, float* __restrict__ dgc,
    int* __restrict__ gidx, float* __restrict__ bzc) {
  const int i = blockIdx.x * 256 + threadIdx.x;
  if (i < HADN / 32) {
    // Packed signs of D2[pi_inv(p)]: word p>>5, bit p&31.
    unsigned wrd = 0;
    for (int j = 0; j < 32; ++j) {
      const int p = i * 32 + j;
      wrd |= (__float_as_uint(D2[pi_inv_map(p)]) >> 31) << j;
    }
    D2sgn[i] = wrd;
  }
  if (i < NFEAT) {
    const int j = perm[i];
    // Output o reads Vtilde[pi(pi(perm[o]))]; fold the LDS swizzle in.
    gidx[i] = swz(pi_map(pi_map(j)));
    // Fold D3 gather, both fwht 1/4 norms, and v_cos's 1/(2*pi) argument scale.
    dgc[i] = 0.0625f * INV2PI * D3[j];
    bzc[i] = INV2PI * bias[i];
  }
}

__global__ __launch_bounds__(256) void srf_main(
    const float* __restrict__ x, const float* __restrict__ D1,
    const unsigned* __restrict__ D2sgn, const float* __restrict__ dgc,
    const int* __restrict__ gidx, const float* __restrict__ bzc,
    float* __restrict__ out) {
  __shared__ float lds[HADN];           // 16 KiB
  const int tid = threadIdx.x;
  const long row = blockIdx.x;
  const int l = tid & 63;
  const int w = tid >> 6;               // wave-in-row -> p-bits {10,11}
  const int base = (((l >> 2) & 1) << 2) | ((l & 1) << 5) | (((l >> 3) & 1) << 6)
                 | (((l >> 4) & 1) << 7) | (((l >> 1) & 1) << 8)
                 | (((l >> 5) & 1) << 9) | (w << 10);

  // ---- Stage 1+2 fused: load x,D1 direct to registers at the lane's own
  //      fragment addresses (16B-aligned; lane-pairs cover full 128B lines
  //      across the 4 loads), then all butterflies in-register. ----
  float r[16];
  const float* xr = x + row * HADN;
#pragma unroll
  for (int g = 0; g < 4; ++g) {         // g bits -> p-bits {3,4}
    const int p = base | ((g & 1) << 3) | (((g >> 1) & 1) << 4);
    const float4 xv = *(const float4*)(xr + p);
    const float4 dv = *(const float4*)(D1 + p);
    r[g * 4 + 0] = xv.x * dv.x; r[g * 4 + 1] = xv.y * dv.y;
    r[g * 4 + 2] = xv.z * dv.z; r[g * 4 + 3] = xv.w * dv.w;
  }
  const unsigned sw2 = D2sgn[base >> 5] >> (base & 4);

  // fwht #1: Hadamard on p-bits {1,3,4,5}: e-bits {1,2,3} + lane-bit0
  bfly<2>(r); bfly<4>(r); bfly<8>(r);
  dpp_bfly<0xB1>(r, (l & 1) != 0);
  // elementwise D2 signs (permuted into z-space), packed 1 word/lane
#pragma unroll
  for (int e = 0; e < 16; ++e) {
    const int pos = (e & 3) | ((e & 12) << 1);   // e0,e1 -> bits 0,1; e2,e3 -> bits 3,4
    const unsigned m = (sw2 >> pos) << 31;
    r[e] = __int_as_float(__float_as_int(r[e]) ^ m);
  }
  // fwht #2: Hadamard on p-bits {0,3,4,8}: e-bits {0,2,3} + lane-bit1
  bfly<1>(r); bfly<4>(r); bfly<8>(r);
  dpp_bfly<0x4E>(r, (l & 2) != 0);

  // Single LDS write (swizzled -> balanced 8 lanes per 4-bank group).
#pragma unroll
  for (int g = 0; g < 4; ++g) {
    const int p = base | ((g & 1) << 3) | (((g >> 1) & 1) << 4);
    const float4 v = make_float4(r[g * 4 + 0], r[g * 4 + 1], r[g * 4 + 2], r[g * 4 + 3]);
    *(float4*)(&lds[swz(p)]) = v;
  }

  // Stage-3 tables: issue before the barrier so latency hides under the wait.
  const int o0 = tid * 4;
  const int o1 = (256 + tid) * 4;
  const int4   gi0 = *(const int4*)(gidx + o0);
  const float4 dg0 = *(const float4*)(dgc + o0);
  const float4 bz0 = *(const float4*)(bzc + o0);
  const int4   gi1 = *(const int4*)(gidx + o1);
  const float4 dg1 = *(const float4*)(dgc + o1);
  const float4 bz1 = *(const float4*)(bzc + o1);
  __syncthreads();

  // ---- Stage 3: permuted gather, cos epilogue, coalesced nt float4 store ----
  float* op = out + row * NFEAT;
  floatx4 res0;
  res0.x = 0.03125f * __builtin_amdgcn_cosf(fmaf(lds[gi0.x], dg0.x, bz0.x));
  res0.y = 0.03125f * __builtin_amdgcn_cosf(fmaf(lds[gi0.y], dg0.y, bz0.y));
  res0.z = 0.03125f * __builtin_amdgcn_cosf(fmaf(lds[gi0.z], dg0.z, bz0.z));
  res0.w = 0.03125f * __builtin_amdgcn_cosf(fmaf(lds[gi0.w], dg0.w, bz0.w));
  __builtin_nontemporal_store(res0, (floatx4*)(op + o0));
  floatx4 res1;
  res1.x = 0.03125f * __builtin_amdgcn_cosf(fmaf(lds[gi1.x], dg1.x, bz1.x));
  res1.y = 0.03125f * __builtin_amdgcn_cosf(fmaf(lds[gi1.y], dg1.y, bz1.y));
  res1.z = 0.03125f * __builtin_amdgcn_cosf(fmaf(lds[gi1.z], dg1.z, bz1.z));
  res1.w = 0.03125f * __builtin_amdgcn_cosf(fmaf(lds[gi1.w], dg1.w, bz1.w));
  __builtin_nontemporal_store(res1, (floatx4*)(op + o1));
}

extern "C" void kernel_launch(void* const* d_in, const int* in_sizes, int n_in,
                              void* d_out, int out_size, void* d_ws, size_t ws_size,
                              hipStream_t stream) {
  const float* x    = (const float*)d_in[0];
  const float* D1   = (const float*)d_in[1];
  const float* D2   = (const float*)d_in[2];
  const float* D3   = (const float*)d_in[3];
  const float* bias = (const float*)d_in[4];
  const int*   perm = (const int*)d_in[5];
  float* out = (float*)d_out;

  unsigned* D2sgn = (unsigned*)d_ws;        // 128 u32
  float*    dgc   = (float*)(D2sgn + 128);  // 2048 f32
  int*      gidx  = (int*)(dgc + NFEAT);    // 2048 i32
  float*    bzc   = (float*)(gidx + NFEAT); // 2048 f32

  srf_setup<<<8, 256, 0, stream>>>(D2, D3, perm, bias, D2sgn, dgc, gidx, bzc);
  srf_main<<<8192, 256, 0, stream>>>(x, D1, D2sgn, dgc, gidx, bzc, out);
}

// Round 6
// 40.871 us; speedup vs baseline: 1.2286x; 1.2286x over previous
//
#include <hip/hip_runtime.h>

#define HADN 4096
#define NFEAT 2048
#define INV2PI 0.15915494309189535f

typedef float floatx4 __attribute__((ext_vector_type(4)));
typedef const __attribute__((address_space(1))) void* gas_cptr;
typedef __attribute__((address_space(3))) void* las_ptr;

// Async global->LDS DMA, 16B per lane. Address-space casts via integer
// round-trip (generic->AS(1)/AS(3) direct casts are rejected by clang).
// LDS dest is wave-uniform base + lane*16; our dest IS linear in lane.
__device__ __forceinline__ void gload_lds16(const float* g, float* l) {
  __builtin_amdgcn_global_load_lds(
      (gas_cptr)(unsigned long long)g,
      (las_ptr)(unsigned)(unsigned long long)l, 16, 0, 0);
}

// out-bit <- in-axis mapping of one reference "fwht" (derived by axis tracking):
// bit0<-a6, bit1<-H(a3), bit2<-a7, bit3<-a0, bit4<-a8, bit5<-H(a4),
// bit6<-a9, bit7<-a2, bit8<-a10, bit9<-H(a5), bit10<-a11, bit11<-H(a1)
__device__ __host__ __forceinline__ int pi_map(int q) {
  return  (((q >> 3) & 1))
        | (((q >> 11) & 1) << 1)
        | (((q >> 7) & 1) << 2)
        | (((q >> 1) & 1) << 3)
        | (((q >> 5) & 1) << 4)
        | (((q >> 9) & 1) << 5)
        | (((q >> 0) & 1) << 6)
        | (((q >> 2) & 1) << 7)
        | (((q >> 4) & 1) << 8)
        | (((q >> 6) & 1) << 9)
        | (((q >> 8) & 1) << 10)
        | (((q >> 10) & 1) << 11);
}

__device__ __host__ __forceinline__ int pi_inv_map(int p) {
  return  (((p >> 6) & 1))
        | (((p >> 3) & 1) << 1)
        | (((p >> 7) & 1) << 2)
        | (((p >> 0) & 1) << 3)
        | (((p >> 8) & 1) << 4)
        | (((p >> 4) & 1) << 5)
        | (((p >> 9) & 1) << 6)
        | (((p >> 2) & 1) << 7)
        | (((p >> 10) & 1) << 8)
        | (((p >> 5) & 1) << 9)
        | (((p >> 11) & 1) << 10)
        | (((p >> 1) & 1) << 11);
}

// LDS bank swizzle: XOR bits {6,7,8}^{9,10,11} into bits {2,3,4}.
// Intra-128B-line permutation (only float-index bits 2..4 flip), so
// pre-swizzling the GLOBAL source keeps full-line coalescing per instruction.
__device__ __forceinline__ int swz(int p) {
  return p ^ ((((p >> 6) ^ (p >> 9)) & 7) << 2);
}

template <int BIT>
__device__ __forceinline__ void bfly(float* r) {
#pragma unroll
  for (int e = 0; e < 16; ++e) {
    if ((e & BIT) == 0) {
      const int f = e | BIT;
      const float a = r[e], b = r[f];
      r[e] = a + b;
      r[f] = a - b;
    }
  }
}

// Cross-lane butterfly via DPP quad-perm (VALU, not DS pipe).
// CTRL=0xB1 -> lane^1, CTRL=0x4E -> lane^2. `upper` lane computes partner-own.
template <int CTRL>
__device__ __forceinline__ void dpp_bfly(float* r, bool upper) {
  const unsigned sm = upper ? 0x80000000u : 0u;
#pragma unroll
  for (int e = 0; e < 16; ++e) {
    const int pv = __builtin_amdgcn_update_dpp(
        0, __float_as_int(r[e]), CTRL, 0xF, 0xF, true);
    r[e] = __int_as_float(pv) + __int_as_float(__float_as_int(r[e]) ^ sm);
  }
}

__global__ __launch_bounds__(256) void srf_setup(
    const float* __restrict__ D1, const float* __restrict__ D2,
    const float* __restrict__ D3, const int* __restrict__ perm,
    const float* __restrict__ bias,
    unsigned* __restrict__ D1sgn, unsigned* __restrict__ D2sgn,
    float* __restrict__ dgc, int* __restrict__ gidx,
    float* __restrict__ bzc) {
  const int i = blockIdx.x * 256 + threadIdx.x;
  if (i < HADN / 32) {
    // D1 signs: input-space, linear. D2 signs: z-space (D2[pi_inv(p)]).
    unsigned w1 = 0, w2 = 0;
    for (int j = 0; j < 32; ++j) {
      const int p = i * 32 + j;
      w1 |= (__float_as_uint(D1[p]) >> 31) << j;
      w2 |= (__float_as_uint(D2[pi_inv_map(p)]) >> 31) << j;
    }
    D1sgn[i] = w1;
    D2sgn[i] = w2;
  }
  if (i < NFEAT) {
    const int j = perm[i];
    // Output o reads Vtilde[pi(pi(perm[o]))]; fold the LDS swizzle in.
    gidx[i] = swz(pi_map(pi_map(j)));
    // Fold D3 gather, both fwht 1/4 norms, and v_cos's 1/(2*pi) arg scale.
    dgc[i] = 0.0625f * INV2PI * D3[j];
    bzc[i] = INV2PI * bias[i];
  }
}

__global__ __launch_bounds__(256) void srf_main(
    const float* __restrict__ x,
    const unsigned* __restrict__ D1sgn, const unsigned* __restrict__ D2sgn,
    const float* __restrict__ dgc, const int* __restrict__ gidx,
    const float* __restrict__ bzc, float* __restrict__ out) {
  __shared__ float lds[HADN];           // 16 KiB -> 8 blocks/CU (wave-capped)
  const int tid = threadIdx.x;
  const long row = blockIdx.x;
  const int l = tid & 63;
  const int w = tid >> 6;               // wave-in-row -> p-bits {10,11}
  const int base = (((l >> 2) & 1) << 2) | ((l & 1) << 5) | (((l >> 3) & 1) << 6)
                 | (((l >> 4) & 1) << 7) | (((l >> 1) & 1) << 8)
                 | (((l >> 5) & 1) << 9) | (w << 10);

  // ---- Stage 1: async DMA x -> LDS, pre-swizzled source, linear dest.
  //      LDS[q] = x[swz(q)]  =>  LDS[swz(p)] = x[p] (swz is an involution).
  const float* xr = x + row * HADN;
#pragma unroll
  for (int k = 0; k < 4; ++k) {
    const int p = (k * 256 + tid) * 4;  // linear dest float index
    gload_lds16(xr + swz(p), &lds[p]);
  }

  // Sign words + stage-3 tables: issue before the barrier (latency hides
  // under the DMA drain).
  const unsigned sw1 = D1sgn[base >> 5] >> (base & 4);
  const unsigned sw2 = D2sgn[base >> 5] >> (base & 4);
  const int o0 = tid * 4;
  const int o1 = (256 + tid) * 4;
  const int4   gi0 = *(const int4*)(gidx + o0);
  const float4 dg0 = *(const float4*)(dgc + o0);
  const float4 bz0 = *(const float4*)(bzc + o0);
  const int4   gi1 = *(const int4*)(gidx + o1);
  const float4 dg1 = *(const float4*)(dgc + o1);
  const float4 bz1 = *(const float4*)(bzc + o1);
  __syncthreads();

  // ---- Stage 2: 16 elems/lane; p-bits {0,1,3,4} thread-local,
  //      p-bit5 on lane-bit0 (DPP xor1), p-bit8 on lane-bit1 (DPP xor2) ----
  float r[16];
#pragma unroll
  for (int g = 0; g < 4; ++g) {         // g bits -> p-bits {3,4}
    const int p = base | ((g & 1) << 3) | (((g >> 1) & 1) << 4);
    const float4 v = *(const float4*)(&lds[swz(p)]);
    r[g * 4 + 0] = v.x; r[g * 4 + 1] = v.y; r[g * 4 + 2] = v.z; r[g * 4 + 3] = v.w;
  }
  // D1 signs (input space), packed 1 word/lane.
#pragma unroll
  for (int e = 0; e < 16; ++e) {
    const int pos = (e & 3) | ((e & 12) << 1);   // e0,e1 -> bits 0,1; e2,e3 -> bits 3,4
    r[e] = __int_as_float(__float_as_int(r[e]) ^ ((sw1 >> pos) << 31));
  }
  // fwht #1: Hadamard on p-bits {1,3,4,5}: e-bits {1,2,3} + lane-bit0
  bfly<2>(r); bfly<4>(r); bfly<8>(r);
  dpp_bfly<0xB1>(r, (l & 1) != 0);
  // D2 signs (permuted into z-space), packed 1 word/lane.
#pragma unroll
  for (int e = 0; e < 16; ++e) {
    const int pos = (e & 3) | ((e & 12) << 1);
    r[e] = __int_as_float(__float_as_int(r[e]) ^ ((sw2 >> pos) << 31));
  }
  // fwht #2: Hadamard on p-bits {0,3,4,8}: e-bits {0,2,3} + lane-bit1
  bfly<1>(r); bfly<4>(r); bfly<8>(r);
  dpp_bfly<0x4E>(r, (l & 2) != 0);

  // Single LDS write (swizzled -> balanced 8 lanes per 4-bank group).
#pragma unroll
  for (int g = 0; g < 4; ++g) {
    const int p = base | ((g & 1) << 3) | (((g >> 1) & 1) << 4);
    const float4 v = make_float4(r[g * 4 + 0], r[g * 4 + 1], r[g * 4 + 2], r[g * 4 + 3]);
    *(float4*)(&lds[swz(p)]) = v;
  }
  __syncthreads();

  // ---- Stage 3: permuted gather, cos epilogue, coalesced nt float4 store ----
  float* op = out + row * NFEAT;
  floatx4 res0;
  res0.x = 0.03125f * __builtin_amdgcn_cosf(fmaf(lds[gi0.x], dg0.x, bz0.x));
  res0.y = 0.03125f * __builtin_amdgcn_cosf(fmaf(lds[gi0.y], dg0.y, bz0.y));
  res0.z = 0.03125f * __builtin_amdgcn_cosf(fmaf(lds[gi0.z], dg0.z, bz0.z));
  res0.w = 0.03125f * __builtin_amdgcn_cosf(fmaf(lds[gi0.w], dg0.w, bz0.w));
  __builtin_nontemporal_store(res0, (floatx4*)(op + o0));
  floatx4 res1;
  res1.x = 0.03125f * __builtin_amdgcn_cosf(fmaf(lds[gi1.x], dg1.x, bz1.x));
  res1.y = 0.03125f * __builtin_amdgcn_cosf(fmaf(lds[gi1.y], dg1.y, bz1.y));
  res1.z = 0.03125f * __builtin_amdgcn_cosf(fmaf(lds[gi1.z], dg1.z, bz1.z));
  res1.w = 0.03125f * __builtin_amdgcn_cosf(fmaf(lds[gi1.w], dg1.w, bz1.w));
  __builtin_nontemporal_store(res1, (floatx4*)(op + o1));
}

extern "C" void kernel_launch(void* const* d_in, const int* in_sizes, int n_in,
                              void* d_out, int out_size, void* d_ws, size_t ws_size,
                              hipStream_t stream) {
  const float* x    = (const float*)d_in[0];
  const float* D1   = (const float*)d_in[1];
  const float* D2   = (const float*)d_in[2];
  const float* D3   = (const float*)d_in[3];
  const float* bias = (const float*)d_in[4];
  const int*   perm = (const int*)d_in[5];
  float* out = (float*)d_out;

  unsigned* D1sgn = (unsigned*)d_ws;        // 128 u32
  unsigned* D2sgn = D1sgn + 128;            // 128 u32
  float*    dgc   = (float*)(D2sgn + 128);  // 2048 f32
  int*      gidx  = (int*)(dgc + NFEAT);    // 2048 i32
  float*    bzc   = (float*)(gidx + NFEAT); // 2048 f32

  srf_setup<<<8, 256, 0, stream>>>(D1, D2, D3, perm, bias,
                                   D1sgn, D2sgn, dgc, gidx, bzc);
  srf_main<<<8192, 256, 0, stream>>>(x, D1sgn, D2sgn, dgc, gidx, bzc, out);
}

// Round 7
// 40.709 us; speedup vs baseline: 1.2335x; 1.0040x over previous
//
#include <hip/hip_runtime.h>

#define HADN 4096
#define NFEAT 2048
#define INV2PI 0.15915494309189535f

typedef float floatx4 __attribute__((ext_vector_type(4)));
typedef const __attribute__((address_space(1))) void* gas_cptr;
typedef __attribute__((address_space(3))) void* las_ptr;

// Async global->LDS DMA, 16B per lane. Address-space casts via integer
// round-trip (generic->AS(1)/AS(3) direct casts are rejected by clang).
// LDS dest must be wave-uniform base + lane*16; our dest IS linear in lane.
__device__ __forceinline__ void gload_lds16(const float* g, float* l) {
  __builtin_amdgcn_global_load_lds(
      (gas_cptr)(unsigned long long)g,
      (las_ptr)(unsigned)(unsigned long long)l, 16, 0, 0);
}

// out-bit <- in-axis mapping of one reference "fwht" (derived by axis tracking):
// bit0<-a6, bit1<-H(a3), bit2<-a7, bit3<-a0, bit4<-a8, bit5<-H(a4),
// bit6<-a9, bit7<-a2, bit8<-a10, bit9<-H(a5), bit10<-a11, bit11<-H(a1)
__device__ __host__ __forceinline__ int pi_map(int q) {
  return  (((q >> 3) & 1))
        | (((q >> 11) & 1) << 1)
        | (((q >> 7) & 1) << 2)
        | (((q >> 1) & 1) << 3)
        | (((q >> 5) & 1) << 4)
        | (((q >> 9) & 1) << 5)
        | (((q >> 0) & 1) << 6)
        | (((q >> 2) & 1) << 7)
        | (((q >> 4) & 1) << 8)
        | (((q >> 6) & 1) << 9)
        | (((q >> 8) & 1) << 10)
        | (((q >> 10) & 1) << 11);
}

__device__ __host__ __forceinline__ int pi_inv_map(int p) {
  return  (((p >> 6) & 1))
        | (((p >> 3) & 1) << 1)
        | (((p >> 7) & 1) << 2)
        | (((p >> 0) & 1) << 3)
        | (((p >> 8) & 1) << 4)
        | (((p >> 4) & 1) << 5)
        | (((p >> 9) & 1) << 6)
        | (((p >> 2) & 1) << 7)
        | (((p >> 10) & 1) << 8)
        | (((p >> 5) & 1) << 9)
        | (((p >> 11) & 1) << 10)
        | (((p >> 1) & 1) << 11);
}

// LDS bank swizzle: XOR bits {6,7,8}^{9,10,11} into bits {2,3,4}.
// Intra-128B-line permutation (only float-index bits 2..4 flip), so
// pre-swizzling the GLOBAL source keeps full-line coalescing per instruction.
__device__ __forceinline__ int swz(int p) {
  return p ^ ((((p >> 6) ^ (p >> 9)) & 7) << 2);
}

template <int BIT>
__device__ __forceinline__ void bfly(float* r) {
#pragma unroll
  for (int e = 0; e < 16; ++e) {
    if ((e & BIT) == 0) {
      const int f = e | BIT;
      const float a = r[e], b = r[f];
      r[e] = a + b;
      r[f] = a - b;
    }
  }
}

// Cross-lane butterfly via DPP quad-perm (VALU, not DS pipe).
// CTRL=0xB1 -> lane^1, CTRL=0x4E -> lane^2. `upper` lane computes partner-own.
template <int CTRL>
__device__ __forceinline__ void dpp_bfly(float* r, bool upper) {
  const unsigned sm = upper ? 0x80000000u : 0u;
#pragma unroll
  for (int e = 0; e < 16; ++e) {
    const int pv = __builtin_amdgcn_update_dpp(
        0, __float_as_int(r[e]), CTRL, 0xF, 0xF, true);
    r[e] = __int_as_float(pv) + __int_as_float(__float_as_int(r[e]) ^ sm);
  }
}

__global__ __launch_bounds__(256) void srf_setup(
    const float* __restrict__ D1, const float* __restrict__ D2,
    const float* __restrict__ D3, const int* __restrict__ perm,
    const float* __restrict__ bias,
    unsigned* __restrict__ D1sgn, unsigned* __restrict__ D2sgn,
    float* __restrict__ dgc, int* __restrict__ gidx,
    float* __restrict__ bzc) {
  const int i = blockIdx.x * 256 + threadIdx.x;
  if (i < HADN / 32) {
    // D1 signs: input-space, linear. D2 signs: z-space (D2[pi_inv(p)]).
    unsigned w1 = 0, w2 = 0;
    for (int j = 0; j < 32; ++j) {
      const int p = i * 32 + j;
      w1 |= (__float_as_uint(D1[p]) >> 31) << j;
      w2 |= (__float_as_uint(D2[pi_inv_map(p)]) >> 31) << j;
    }
    D1sgn[i] = w1;
    D2sgn[i] = w2;
  }
  if (i < NFEAT) {
    const int j = perm[i];
    // Output o reads Vtilde[pi(pi(perm[o]))]; fold the LDS swizzle in.
    gidx[i] = swz(pi_map(pi_map(j)));
    // Fold D3 gather, both fwht 1/4 norms, and v_cos's 1/(2*pi) arg scale.
    dgc[i] = 0.0625f * INV2PI * D3[j];
    bzc[i] = INV2PI * bias[i];
  }
}

// 512 threads, 2 rows per block. Per-thread work identical to the 1-row
// version (16 elems of ONE row); barriers and stage-3 table loads are
// amortized over 2 rows, occupancy = 4 blocks x 8 waves = 32 waves/CU.
__global__ __launch_bounds__(512) void srf_main(
    const float* __restrict__ x,
    const unsigned* __restrict__ D1sgn, const unsigned* __restrict__ D2sgn,
    const float* __restrict__ dgc, const int* __restrict__ gidx,
    const float* __restrict__ bzc, float* __restrict__ out) {
  __shared__ float lds[2][HADN];        // 32 KiB
  const int tid = threadIdx.x;
  const int rr = tid >> 8;              // which of the block's 2 rows
  const int t256 = tid & 255;
  const long row = (long)blockIdx.x * 2;
  const int l = tid & 63;
  const int w = (tid >> 6) & 3;         // wave-in-row -> p-bits {10,11}
  const int base = (((l >> 2) & 1) << 2) | ((l & 1) << 5) | (((l >> 3) & 1) << 6)
                 | (((l >> 4) & 1) << 7) | (((l >> 1) & 1) << 8)
                 | (((l >> 5) & 1) << 9) | (w << 10);

  // ---- Stage 1: async DMA x -> LDS, pre-swizzled source, linear dest.
  //      LDS[rr][q] = x_row[swz(q)]  =>  LDS[rr][swz(p)] = x_row[p].
  const float* xr = x + (row + rr) * HADN;
#pragma unroll
  for (int k = 0; k < 4; ++k) {
    const int p = (k * 256 + t256) * 4; // linear dest float index
    gload_lds16(xr + swz(p), &lds[rr][p]);
  }

  // Sign words + stage-3 tables: issue before the barrier (latency hides
  // under the DMA drain). Tables are shared by both rows (same o per thread).
  const unsigned sw1 = D1sgn[base >> 5] >> (base & 4);
  const unsigned sw2 = D2sgn[base >> 5] >> (base & 4);
  const int o = tid * 4;                // 512 threads x 4 = all 2048 outputs
  const int4   gi = *(const int4*)(gidx + o);
  const float4 dg = *(const float4*)(dgc + o);
  const float4 bz = *(const float4*)(bzc + o);
  __syncthreads();

  // ---- Stage 2: 16 elems/lane of row rr; p-bits {0,1,3,4} thread-local,
  //      p-bit5 on lane-bit0 (DPP xor1), p-bit8 on lane-bit1 (DPP xor2) ----
  float r[16];
  float* L = &lds[rr][0];
#pragma unroll
  for (int g = 0; g < 4; ++g) {         // g bits -> p-bits {3,4}
    const int p = base | ((g & 1) << 3) | (((g >> 1) & 1) << 4);
    const float4 v = *(const float4*)(L + swz(p));
    r[g * 4 + 0] = v.x; r[g * 4 + 1] = v.y; r[g * 4 + 2] = v.z; r[g * 4 + 3] = v.w;
  }
  // D1 signs (input space), packed 1 word/lane.
#pragma unroll
  for (int e = 0; e < 16; ++e) {
    const int pos = (e & 3) | ((e & 12) << 1);   // e0,e1 -> bits 0,1; e2,e3 -> bits 3,4
    r[e] = __int_as_float(__float_as_int(r[e]) ^ ((sw1 >> pos) << 31));
  }
  // fwht #1: Hadamard on p-bits {1,3,4,5}: e-bits {1,2,3} + lane-bit0
  bfly<2>(r); bfly<4>(r); bfly<8>(r);
  dpp_bfly<0xB1>(r, (l & 1) != 0);
  // D2 signs (permuted into z-space), packed 1 word/lane.
#pragma unroll
  for (int e = 0; e < 16; ++e) {
    const int pos = (e & 3) | ((e & 12) << 1);
    r[e] = __int_as_float(__float_as_int(r[e]) ^ ((sw2 >> pos) << 31));
  }
  // fwht #2: Hadamard on p-bits {0,3,4,8}: e-bits {0,2,3} + lane-bit1
  bfly<1>(r); bfly<4>(r); bfly<8>(r);
  dpp_bfly<0x4E>(r, (l & 2) != 0);

  // Single LDS write (swizzled -> balanced 8 lanes per 4-bank group).
#pragma unroll
  for (int g = 0; g < 4; ++g) {
    const int p = base | ((g & 1) << 3) | (((g >> 1) & 1) << 4);
    const float4 v = make_float4(r[g * 4 + 0], r[g * 4 + 1], r[g * 4 + 2], r[g * 4 + 3]);
    *(float4*)(L + swz(p)) = v;
  }
  __syncthreads();

  // ---- Stage 3: permuted gather, cos epilogue, coalesced nt float4 store.
  //      Same o for both rows -> tables loaded once per block. ----
  float* op = out + row * NFEAT;
  floatx4 res0;
  res0.x = 0.03125f * __builtin_amdgcn_cosf(fmaf(lds[0][gi.x], dg.x, bz.x));
  res0.y = 0.03125f * __builtin_amdgcn_cosf(fmaf(lds[0][gi.y], dg.y, bz.y));
  res0.z = 0.03125f * __builtin_amdgcn_cosf(fmaf(lds[0][gi.z], dg.z, bz.z));
  res0.w = 0.03125f * __builtin_amdgcn_cosf(fmaf(lds[0][gi.w], dg.w, bz.w));
  __builtin_nontemporal_store(res0, (floatx4*)(op + o));
  floatx4 res1;
  res1.x = 0.03125f * __builtin_amdgcn_cosf(fmaf(lds[1][gi.x], dg.x, bz.x));
  res1.y = 0.03125f * __builtin_amdgcn_cosf(fmaf(lds[1][gi.y], dg.y, bz.y));
  res1.z = 0.03125f * __builtin_amdgcn_cosf(fmaf(lds[1][gi.z], dg.z, bz.z));
  res1.w = 0.03125f * __builtin_amdgcn_cosf(fmaf(lds[1][gi.w], dg.w, bz.w));
  __builtin_nontemporal_store(res1, (floatx4*)(op + NFEAT + o));
}

extern "C" void kernel_launch(void* const* d_in, const int* in_sizes, int n_in,
                              void* d_out, int out_size, void* d_ws, size_t ws_size,
                              hipStream_t stream) {
  const float* x    = (const float*)d_in[0];
  const float* D1   = (const float*)d_in[1];
  const float* D2   = (const float*)d_in[2];
  const float* D3   = (const float*)d_in[3];
  const float* bias = (const float*)d_in[4];
  const int*   perm = (const int*)d_in[5];
  float* out = (float*)d_out;

  unsigned* D1sgn = (unsigned*)d_ws;        // 128 u32
  unsigned* D2sgn = D1sgn + 128;            // 128 u32
  float*    dgc   = (float*)(D2sgn + 128);  // 2048 f32
  int*      gidx  = (int*)(dgc + NFEAT);    // 2048 i32
  float*    bzc   = (float*)(gidx + NFEAT); // 2048 f32

  srf_setup<<<8, 256, 0, stream>>>(D1, D2, D3, perm, bias,
                                   D1sgn, D2sgn, dgc, gidx, bzc);
  srf_main<<<4096, 512, 0, stream>>>(x, D1sgn, D2sgn, dgc, gidx, bzc, out);
}

// Round 8
// 40.008 us; speedup vs baseline: 1.2551x; 1.0175x over previous
//
#include <hip/hip_runtime.h>

#define HADN 4096
#define NFEAT 2048
#define INV2PI 0.15915494309189535f

typedef float floatx4 __attribute__((ext_vector_type(4)));
typedef const __attribute__((address_space(1))) void* gas_cptr;
typedef __attribute__((address_space(3))) void* las_ptr;

// Async global->LDS DMA, 16B per lane. Address-space casts via integer
// round-trip (generic->AS(1)/AS(3) direct casts are rejected by clang).
// LDS dest must be wave-uniform base + lane*16; our dest IS linear in lane.
__device__ __forceinline__ void gload_lds16(const float* g, float* l) {
  __builtin_amdgcn_global_load_lds(
      (gas_cptr)(unsigned long long)g,
      (las_ptr)(unsigned)(unsigned long long)l, 16, 0, 0);
}

// out-bit <- in-axis mapping of one reference "fwht" (derived by axis tracking):
// bit0<-a6, bit1<-H(a3), bit2<-a7, bit3<-a0, bit4<-a8, bit5<-H(a4),
// bit6<-a9, bit7<-a2, bit8<-a10, bit9<-H(a5), bit10<-a11, bit11<-H(a1)
__device__ __host__ __forceinline__ int pi_map(int q) {
  return  (((q >> 3) & 1))
        | (((q >> 11) & 1) << 1)
        | (((q >> 7) & 1) << 2)
        | (((q >> 1) & 1) << 3)
        | (((q >> 5) & 1) << 4)
        | (((q >> 9) & 1) << 5)
        | (((q >> 0) & 1) << 6)
        | (((q >> 2) & 1) << 7)
        | (((q >> 4) & 1) << 8)
        | (((q >> 6) & 1) << 9)
        | (((q >> 8) & 1) << 10)
        | (((q >> 10) & 1) << 11);
}

__device__ __host__ __forceinline__ int pi_inv_map(int p) {
  return  (((p >> 6) & 1))
        | (((p >> 3) & 1) << 1)
        | (((p >> 7) & 1) << 2)
        | (((p >> 0) & 1) << 3)
        | (((p >> 8) & 1) << 4)
        | (((p >> 4) & 1) << 5)
        | (((p >> 9) & 1) << 6)
        | (((p >> 2) & 1) << 7)
        | (((p >> 10) & 1) << 8)
        | (((p >> 5) & 1) << 9)
        | (((p >> 11) & 1) << 10)
        | (((p >> 1) & 1) << 11);
}

// LDS bank swizzle: XOR bits {6,7,8}^{9,10,11} into bits {2,3,4}.
// Intra-128B-line permutation (only float-index bits 2..4 flip), so
// pre-swizzling the GLOBAL source keeps full-line coalescing per instruction.
__device__ __forceinline__ int swz(int p) {
  return p ^ ((((p >> 6) ^ (p >> 9)) & 7) << 2);
}

template <int BIT>
__device__ __forceinline__ void bfly(float* r) {
#pragma unroll
  for (int e = 0; e < 16; ++e) {
    if ((e & BIT) == 0) {
      const int f = e | BIT;
      const float a = r[e], b = r[f];
      r[e] = a + b;
      r[f] = a - b;
    }
  }
}

// Cross-lane butterfly via DPP quad-perm (VALU, not DS pipe).
// CTRL=0xB1 -> lane^1, CTRL=0x4E -> lane^2. `upper` lane computes partner-own.
template <int CTRL>
__device__ __forceinline__ void dpp_bfly(float* r, bool upper) {
  const unsigned sm = upper ? 0x80000000u : 0u;
#pragma unroll
  for (int e = 0; e < 16; ++e) {
    const int pv = __builtin_amdgcn_update_dpp(
        0, __float_as_int(r[e]), CTRL, 0xF, 0xF, true);
    r[e] = __int_as_float(pv) + __int_as_float(__float_as_int(r[e]) ^ sm);
  }
}

// Fully parallel setup: one thread per Hadamard index; sign packing via
// __ballot (64-bit mask; lanes 0 and 32 write the two 32-bit words).
__global__ __launch_bounds__(256) void srf_setup(
    const float* __restrict__ D1, const float* __restrict__ D2,
    const float* __restrict__ D3, const int* __restrict__ perm,
    const float* __restrict__ bias,
    unsigned* __restrict__ D1sgn, unsigned* __restrict__ D2sgn,
    float* __restrict__ dgc, int* __restrict__ gidx,
    float* __restrict__ bzc) {
  const int i = blockIdx.x * 256 + threadIdx.x;   // 0..4095 (16 blocks)
  // D1 signs: input-space, linear. D2 signs: z-space (D2[pi_inv(p)]).
  const bool b1 = (__float_as_uint(D1[i]) >> 31) != 0;
  const bool b2 = (__float_as_uint(D2[pi_inv_map(i)]) >> 31) != 0;
  const unsigned long long m1 = __ballot(b1);
  const unsigned long long m2 = __ballot(b2);
  const int lane = i & 63;
  if ((lane & 31) == 0) {
    D1sgn[i >> 5] = (unsigned)(m1 >> (lane & 32));
    D2sgn[i >> 5] = (unsigned)(m2 >> (lane & 32));
  }
  if (i < NFEAT) {
    const int j = perm[i];
    // Output o reads Vtilde[pi(pi(perm[o]))]; fold the LDS swizzle in.
    gidx[i] = swz(pi_map(pi_map(j)));
    // Fold D3 gather, both fwht 1/4 norms, and v_cos's 1/(2*pi) arg scale.
    dgc[i] = 0.0625f * INV2PI * D3[j];
    bzc[i] = INV2PI * bias[i];
  }
}

// 512 threads, 2 rows per block. Per-thread work identical to the 1-row
// version (16 elems of ONE row); barriers and stage-3 table loads are
// amortized over 2 rows, occupancy = 4 blocks x 8 waves = 32 waves/CU.
__global__ __launch_bounds__(512) void srf_main(
    const float* __restrict__ x,
    const unsigned* __restrict__ D1sgn, const unsigned* __restrict__ D2sgn,
    const float* __restrict__ dgc, const int* __restrict__ gidx,
    const float* __restrict__ bzc, float* __restrict__ out) {
  __shared__ float lds[2][HADN];        // 32 KiB
  const int tid = threadIdx.x;
  const int rr = tid >> 8;              // which of the block's 2 rows
  const int t256 = tid & 255;
  const long row = (long)blockIdx.x * 2;
  const int l = tid & 63;
  const int w = (tid >> 6) & 3;         // wave-in-row -> p-bits {10,11}
  const int base = (((l >> 2) & 1) << 2) | ((l & 1) << 5) | (((l >> 3) & 1) << 6)
                 | (((l >> 4) & 1) << 7) | (((l >> 1) & 1) << 8)
                 | (((l >> 5) & 1) << 9) | (w << 10);

  // ---- Stage 1: async DMA x -> LDS, pre-swizzled source, linear dest.
  //      LDS[rr][q] = x_row[swz(q)]  =>  LDS[rr][swz(p)] = x_row[p].
  const float* xr = x + (row + rr) * HADN;
#pragma unroll
  for (int k = 0; k < 4; ++k) {
    const int p = (k * 256 + t256) * 4; // linear dest float index
    gload_lds16(xr + swz(p), &lds[rr][p]);
  }

  // Sign words + stage-3 tables: issue before the barrier (latency hides
  // under the DMA drain). Tables are shared by both rows (same o per thread).
  const unsigned sw1 = D1sgn[base >> 5] >> (base & 4);
  const unsigned sw2 = D2sgn[base >> 5] >> (base & 4);
  const int o = tid * 4;                // 512 threads x 4 = all 2048 outputs
  const int4   gi = *(const int4*)(gidx + o);
  const float4 dg = *(const float4*)(dgc + o);
  const float4 bz = *(const float4*)(bzc + o);
  __syncthreads();

  // ---- Stage 2: 16 elems/lane of row rr; p-bits {0,1,3,4} thread-local,
  //      p-bit5 on lane-bit0 (DPP xor1), p-bit8 on lane-bit1 (DPP xor2) ----
  float r[16];
  float* L = &lds[rr][0];
#pragma unroll
  for (int g = 0; g < 4; ++g) {         // g bits -> p-bits {3,4}
    const int p = base | ((g & 1) << 3) | (((g >> 1) & 1) << 4);
    const float4 v = *(const float4*)(L + swz(p));
    r[g * 4 + 0] = v.x; r[g * 4 + 1] = v.y; r[g * 4 + 2] = v.z; r[g * 4 + 3] = v.w;
  }
  // D1 signs (input space), packed 1 word/lane.
#pragma unroll
  for (int e = 0; e < 16; ++e) {
    const int pos = (e & 3) | ((e & 12) << 1);   // e0,e1 -> bits 0,1; e2,e3 -> bits 3,4
    r[e] = __int_as_float(__float_as_int(r[e]) ^ ((sw1 >> pos) << 31));
  }
  // fwht #1: Hadamard on p-bits {1,3,4,5}: e-bits {1,2,3} + lane-bit0
  bfly<2>(r); bfly<4>(r); bfly<8>(r);
  dpp_bfly<0xB1>(r, (l & 1) != 0);
  // D2 signs (permuted into z-space), packed 1 word/lane.
#pragma unroll
  for (int e = 0; e < 16; ++e) {
    const int pos = (e & 3) | ((e & 12) << 1);
    r[e] = __int_as_float(__float_as_int(r[e]) ^ ((sw2 >> pos) << 31));
  }
  // fwht #2: Hadamard on p-bits {0,3,4,8}: e-bits {0,2,3} + lane-bit1
  bfly<1>(r); bfly<4>(r); bfly<8>(r);
  dpp_bfly<0x4E>(r, (l & 2) != 0);

  // Single LDS write (swizzled -> balanced 8 lanes per 4-bank group).
#pragma unroll
  for (int g = 0; g < 4; ++g) {
    const int p = base | ((g & 1) << 3) | (((g >> 1) & 1) << 4);
    const float4 v = make_float4(r[g * 4 + 0], r[g * 4 + 1], r[g * 4 + 2], r[g * 4 + 3]);
    *(float4*)(L + swz(p)) = v;
  }
  __syncthreads();

  // ---- Stage 3: permuted gather, cos epilogue, coalesced nt float4 store.
  //      Same o for both rows -> tables loaded once per block. ----
  float* op = out + row * NFEAT;
  floatx4 res0;
  res0.x = 0.03125f * __builtin_amdgcn_cosf(fmaf(lds[0][gi.x], dg.x, bz.x));
  res0.y = 0.03125f * __builtin_amdgcn_cosf(fmaf(lds[0][gi.y], dg.y, bz.y));
  res0.z = 0.03125f * __builtin_amdgcn_cosf(fmaf(lds[0][gi.z], dg.z, bz.z));
  res0.w = 0.03125f * __builtin_amdgcn_cosf(fmaf(lds[0][gi.w], dg.w, bz.w));
  __builtin_nontemporal_store(res0, (floatx4*)(op + o));
  floatx4 res1;
  res1.x = 0.03125f * __builtin_amdgcn_cosf(fmaf(lds[1][gi.x], dg.x, bz.x));
  res1.y = 0.03125f * __builtin_amdgcn_cosf(fmaf(lds[1][gi.y], dg.y, bz.y));
  res1.z = 0.03125f * __builtin_amdgcn_cosf(fmaf(lds[1][gi.z], dg.z, bz.z));
  res1.w = 0.03125f * __builtin_amdgcn_cosf(fmaf(lds[1][gi.w], dg.w, bz.w));
  __builtin_nontemporal_store(res1, (floatx4*)(op + NFEAT + o));
}

extern "C" void kernel_launch(void* const* d_in, const int* in_sizes, int n_in,
                              void* d_out, int out_size, void* d_ws, size_t ws_size,
                              hipStream_t stream) {
  const float* x    = (const float*)d_in[0];
  const float* D1   = (const float*)d_in[1];
  const float* D2   = (const float*)d_in[2];
  const float* D3   = (const float*)d_in[3];
  const float* bias = (const float*)d_in[4];
  const int*   perm = (const int*)d_in[5];
  float* out = (float*)d_out;

  unsigned* D1sgn = (unsigned*)d_ws;        // 128 u32
  unsigned* D2sgn = D1sgn + 128;            // 128 u32
  float*    dgc   = (float*)(D2sgn + 128);  // 2048 f32
  int*      gidx  = (int*)(dgc + NFEAT);    // 2048 i32
  float*    bzc   = (float*)(gidx + NFEAT); // 2048 f32

  srf_setup<<<16, 256, 0, stream>>>(D1, D2, D3, perm, bias,
                                    D1sgn, D2sgn, dgc, gidx, bzc);
  srf_main<<<4096, 512, 0, stream>>>(x, D1sgn, D2sgn, dgc, gidx, bzc, out);
}